// Round 5
// baseline (913.223 us; speedup 1.0000x reference)
//
#include <hip/hip_runtime.h>

#define NN 4096
#define NSTEPS 100
#define TPB 512
#define NBLK 512     // 2 blocks per CU; 8 rows per block, K pinned in VGPRs
#define NROW 8       // rows per block

// Coherent (cross-XCD) 8-byte load/store: relaxed agent-scope atomics compile
// to sc-flagged global ops that bypass the non-coherent L1/L2 and hit the
// coherence point directly — no release/acquire cache-maintenance.
__device__ __forceinline__ void zstore_u64(float2* p, unsigned long long u) {
    __hip_atomic_store((unsigned long long*)p, u, __ATOMIC_RELAXED,
                       __HIP_MEMORY_SCOPE_AGENT);
}
__device__ __forceinline__ unsigned long long zload_u64(const float2* p) {
    return __hip_atomic_load((const unsigned long long*)p, __ATOMIC_RELAXED,
                             __HIP_MEMORY_SCOPE_AGENT);
}

// R6 (on top of R5's early-issue + distributed ODE):
//  - 512 blocks x 8 rows, launch_bounds(512,4): per-thread kA is 8x8=64
//    floats -> genuinely VGPR-resident (R5's 16x8=128 exceeded the 108
//    arch-VGPR allocation, so the compiler shuttled kA through AGPRs/scratch
//    every step — ~half of R5's VALU issue was register-class churn).
//  - 2 co-resident blocks/CU: while one block spin-waits on producer tags,
//    the sibling block's dot issues — the poll RTT is no longer exposed.
//    Co-residency (deadlock-free): 16 waves/CU <= 32, VGPR <= 128 (forced by
//    launch_bounds) -> 16 waves/CU OK, LDS 2 x ~1.1KB. All 512 blocks
//    resident.
//  - Butterfly shrinks to 17 shuffles (16 accs: 4 halving rounds + 2 tree
//    rounds); every lane ends with the FULL-wave sum of acc (lane&15), so
//    only lanes 0..15 write P. P[2][8][17] (pad 17: coprime with 32 banks ->
//    conflict-free column reads in the ODE).
//  - ODE: wave w owns row w; lane 0 keeps persistent (x,y), publishes.
//  LDS parity-reuse safety: each block's 8 waves cover ALL 4096 cols, so a
//  block's tag-(s+1) publish is ordered after ALL its waves' step-s P-reads
//  (via the step-s barrier); transitively no (s+2)-write precedes an
//  (s)-read anywhere (same argument as R5, geometry-adjusted).
__global__ __launch_bounds__(TPB, 4) void k_persist(
    const float* __restrict__ K, const float2* __restrict__ z0,
    float2* __restrict__ zb0, float2* __restrict__ zb1,
    float2* __restrict__ zfinal, const float* __restrict__ omega_p,
    const float* __restrict__ dt_p) {
    __shared__ float P[2][8][17];   // [parity][wave][acc 0..15], pad 17

    const int tid  = threadIdx.x;
    const int bid  = blockIdx.x;
    const int w    = tid >> 6, lane = tid & 63;   // w = column-eighth
    const int colbase = w * 512 + lane;           // col_j = colbase + j*64

    const float omega = *omega_p;
    const float dt    = *dt_p;
    const float inv2n = 1.0f / (2.0f * NN);

    // ---- K fragment: 8 rows x 8 strided cols = 64 scalars in VGPRs ----
    float kA[NROW][8];
#pragma unroll
    for (int r = 0; r < NROW; ++r) {
        const float* Kr = K + (size_t)(bid * NROW + r) * NN + colbase;
#pragma unroll
        for (int j = 0; j < 8; ++j) kA[r][j] = Kr[j * 64];
    }

    // ---- persistent ODE state: wave w's lane 0 holds row bid*8+w ----
    float x = 0.f, y = 0.f;
    if (lane == 0) {
        float2 zc = z0[bid * NROW + w];
        x = zc.x; y = zc.y;
    }

    unsigned long long v[8];   // in-flight tagged loads for the NEXT step

    for (int s = 0; s < NSTEPS; ++s) {
        // Pin kA in registers: opaque redefinition each iteration so the
        // compiler can neither spill-and-reload nor refold the global loads.
#pragma unroll
        for (int r = 0; r < NROW; ++r)
#pragma unroll
            for (int j = 0; j < 8; ++j) asm volatile("" : "+v"(kA[r][j]));

        // ---- gather this thread's 8 z elements into registers ----
        float zre[8], zim[8];
        if (s == 0) {
#pragma unroll
            for (int j = 0; j < 8; ++j) {
                float2 zc = z0[colbase + j * 64];
                zre[j] = zc.x; zim[j] = zc.y;
            }
        } else {
            // v[] was issued at the end of step s-1; finish the poll.
            const float2* zsrc = (s & 1) ? zb1 : zb0;
            const unsigned tag = (unsigned)(s & 7);
            unsigned stale = 0u;
#pragma unroll
            for (int j = 0; j < 8; ++j)
                stale |= (((unsigned)v[j] & 7u) != tag) ? (1u << j) : 0u;
            while (stale) {                      // batched re-poll
                __builtin_amdgcn_s_sleep(1);
#pragma unroll
                for (int j = 0; j < 8; ++j)
                    if (stale & (1u << j))
                        v[j] = zload_u64(zsrc + colbase + j * 64);
#pragma unroll
                for (int j = 0; j < 8; ++j)
                    if ((stale & (1u << j)) && ((unsigned)v[j] & 7u) == tag)
                        stale &= ~(1u << j);
            }
#pragma unroll
            for (int j = 0; j < 8; ++j) {
                union { unsigned u; float f; } cx, cy;
                cx.u = (unsigned)v[j];
                cy.u = (unsigned)(v[j] >> 32);
                zre[j] = cx.f; zim[j] = cy.f;
            }
        }

        // ---- dots: 8 rows x 8 cols per thread, K and z in registers ----
        float sr[NROW], si[NROW];
#pragma unroll
        for (int r = 0; r < NROW; ++r) { sr[r] = 0.f; si[r] = 0.f; }
#pragma unroll
        for (int j = 0; j < 8; ++j) {
#pragma unroll
            for (int r = 0; r < NROW; ++r) {
                sr[r] += kA[r][j] * zre[j];
                si[r] += kA[r][j] * zim[j];
            }
        }

        // ---- EARLY-ISSUE the next step's tagged loads (fly during
        //      butterfly + barrier + ODE; checked at next loop top) ----
        if (s + 1 < NSTEPS) {
            const float2* zn = ((s + 1) & 1) ? zb1 : zb0;
#pragma unroll
            for (int j = 0; j < 8; ++j)
                v[j] = zload_u64(zn + colbase + j * 64);
        }

        // ---- distribute-and-halve butterfly: 17 shuffles/thread ----
        // acc index i: i<8 -> Re(row i); i>=8 -> Im(row i-8).
        // 4 halving rounds on lane bits 0..3, then 2 tree rounds (bits 4,5):
        // every lane ends with acc (lane&15) summed over ALL 64 lanes.
        float a16[16];
#pragma unroll
        for (int r = 0; r < NROW; ++r) { a16[r] = sr[r]; a16[8 + r] = si[r]; }
        float b8[8];
#pragma unroll
        for (int m = 0; m < 8; ++m) {
            float aa = a16[2 * m], bb = a16[2 * m + 1];
            bool hi = lane & 1;
            float snd = hi ? aa : bb, kp = hi ? bb : aa;
            b8[m] = kp + __shfl_xor(snd, 1, 64);
        }
        float b4[4];
#pragma unroll
        for (int m = 0; m < 4; ++m) {
            float aa = b8[2 * m], bb = b8[2 * m + 1];
            bool hi = lane & 2;
            float snd = hi ? aa : bb, kp = hi ? bb : aa;
            b4[m] = kp + __shfl_xor(snd, 2, 64);
        }
        float b2[2];
#pragma unroll
        for (int m = 0; m < 2; ++m) {
            float aa = b2[0] * 0.f + b4[2 * m], bb = b4[2 * m + 1]; // (no-op guard removed by compiler)
            bool hi = lane & 4;
            float snd = hi ? aa : bb, kp = hi ? bb : aa;
            b2[m] = kp + __shfl_xor(snd, 4, 64);
        }
        float red;
        {
            float aa = b2[0], bb = b2[1];
            bool hi = lane & 8;
            float snd = hi ? aa : bb, kp = hi ? bb : aa;
            red = kp + __shfl_xor(snd, 8, 64);
            red += __shfl_xor(red, 16, 64);     // tree: sum lane-bit 4
            red += __shfl_xor(red, 32, 64);     // tree: sum lane-bit 5
            if (lane < 16) P[s & 1][w][lane] = red;
        }
        __syncthreads();

        // ---- per-wave ODE: wave w owns row bid*8+w ----
        {
            const int par = s & 1;
            int q  = lane & 7;                       // source wave
            int ri = (lane >> 3) & 1;                // 0=Re, 1=Im
            float val = P[par][q][ri * 8 + w];
            val += __shfl_xor(val, 1, 64);           // sum over q (xor-closed
            val += __shfl_xor(val, 2, 64);           //  within lanes 0-7 and
            val += __shfl_xor(val, 4, 64);           //  lanes 8-15)
            float other = __shfl_xor(val, 8, 64);    // Im to lane 0
            if (lane == 0) {
                float u  = val;                      // Re(K z) row
                float vv = other;                    // Im(K z) row
                float A = x * x - y * y;             // Re(z^2)
                float B = 2.0f * x * y;              // Im(z^2)
                float dzr = inv2n * (u  - (u * A + vv * B)) + omega * x;
                float dzi = inv2n * (vv - (u * B - vv * A)) + omega * y;
                float nx = x + dt * dzr;
                float ny = y + dt * dzi;
                float a2 = nx * nx + ny * ny;
                if (a2 >= 0.999f * 0.999f) {
                    float sc = 0.999f / sqrtf(a2);
                    nx *= sc; ny *= sc;
                }
                x = nx; y = ny;                      // state stays in regs
                int gr = bid * NROW + w;
                if (s == NSTEPS - 1) {
                    zfinal[gr] = make_float2(nx, ny);   // plain, untagged
                } else {
                    union { float f; unsigned u; } cx, cy;
                    cx.f = nx; cy.f = ny;
                    cx.u = (cx.u & ~7u) | (unsigned)((s + 1) & 7);
                    unsigned long long pk =
                        (unsigned long long)cx.u |
                        ((unsigned long long)cy.u << 32);
                    float2* zo = ((s + 1) & 1) ? zb1 : zb0;
                    zstore_u64(zo + gr, pk);            // fire-and-forget
                }
            }
        }
        // no trailing barrier — P is parity-double-buffered and the tag
        // protocol transitively orders (s+2)-writes after (s)-reads
    }
}

// ---- generic fallback: per-step launches ----
__global__ __launch_bounds__(256) void k_step_f32(
    const float* __restrict__ K, const float2* __restrict__ zin,
    float2* __restrict__ zout, const float* __restrict__ omega_p,
    const float* __restrict__ dt_p, int n) {
    const int wave = threadIdx.x >> 6;
    const int lane = threadIdx.x & 63;
    const int row  = blockIdx.x * 4 + wave;
    if (row >= n) return;
    float sr = 0.0f, si = 0.0f;
    for (int c = lane; c < n; c += 64) {
        float k = K[(size_t)row * n + c];
        float2 z = zin[c];
        sr += k * z.x;
        si += k * z.y;
    }
#pragma unroll
    for (int off = 32; off; off >>= 1) {
        sr += __shfl_down(sr, off, 64);
        si += __shfl_down(si, off, 64);
    }
    if (lane == 0) {
        float u = sr, v = si;
        float2 zc = zin[row];
        float x = zc.x, y = zc.y;
        float inv2n = 1.0f / (2.0f * n);
        float A = x * x - y * y, B = 2.0f * x * y;
        float dzr = inv2n * (u - (u * A + v * B)) + (*omega_p) * x;
        float dzi = inv2n * (v - (u * B - v * A)) + (*omega_p) * y;
        float nx = x + (*dt_p) * dzr, ny = y + (*dt_p) * dzi;
        float a2 = nx * nx + ny * ny;
        if (a2 >= 0.999f * 0.999f) { float sc = 0.999f / sqrtf(a2); nx *= sc; ny *= sc; }
        zout[row] = make_float2(nx, ny);
    }
}

extern "C" void kernel_launch(void* const* d_in, const int* in_sizes, int n_in,
                              void* d_out, int out_size, void* d_ws, size_t ws_size,
                              hipStream_t stream) {
    const float2* z0      = (const float2*)d_in[0];
    const float*  K       = (const float*)d_in[1];
    const float*  omega_p = (const float*)d_in[2];
    const float*  dt_p    = (const float*)d_in[3];
    const int n = in_sizes[0] / 2;
    float2* out = (float2*)d_out;

    const size_t need = 2 * (size_t)NN * sizeof(float2);   // two z buffers
    if (n == NN && ws_size >= need) {
        float2* zb0 = (float2*)d_ws;
        float2* zb1 = zb0 + NN;
        hipMemsetAsync(d_ws, 0, need, stream);   // tag 0 != any live tag (1,2)
        k_persist<<<NBLK, TPB, 0, stream>>>(K, z0, zb0, zb1, out,
                                            omega_p, dt_p);
    } else {
        float2* zb0 = (float2*)d_ws;
        float2* zb1 = zb0 + n;
        const float2* cur = z0;
        for (int s = 0; s < NSTEPS; ++s) {
            float2* nxt = (s == NSTEPS - 1) ? out : ((s & 1) ? zb1 : zb0);
            k_step_f32<<<(n + 3) / 4, 256, 0, stream>>>(K, cur, nxt, omega_p, dt_p, n);
            cur = nxt;
        }
    }
}